// Round 3
// baseline (197.058 us; speedup 1.0000x reference)
//
#include <hip/hip_runtime.h>

#define NCOLS 65536
#define NROWS 256
#define HID 64

// g3(p,s) lookup table: p in [-0.5,0.5] x s in [0,1)
#define TP 64             // p grid points
#define TS 64             // s grid points
#define TST 68            // padded LDS row stride in words (68%32=4, float4-aligned)
#define PSCALE 63.0f      // TP-1
#define SSCALE 63.0f      // TS-1

#define CPB 1024          // cols per block (4 per thread)
#define RPB 16            // rows per block
#define THREADS 256       // grid = 64 x 16 = 1024 blocks = exactly 4/CU

// ---- builder: exact MLP evaluated on the (p,s) grid with ib = i_b[0] ----
__global__ void soen_build(const float* __restrict__ i_b, const float* __restrict__ w1,
                           const float* __restrict__ b1, const float* __restrict__ w2,
                           const float* __restrict__ b2, float* __restrict__ tabg)
{
    const int e = blockIdx.x * blockDim.x + threadIdx.x;   // grid sized exactly TP*TS
    const int ip = e / TS;
    const int is = e - ip * TS;
    const float p  = -0.5f + (float)ip * (1.0f / PSCALE);
    const float sv = (float)is * (1.0f / SSCALE);
    const float ib = i_b[0];
    float acc = b2[0];
    #pragma unroll 4
    for (int j = 0; j < HID; j++) {
        const float a = fmaf(p, w1[j], fmaf(sv, w1[HID + j], fmaf(ib, w1[2 * HID + j], b1[j])));
        const float ex = __builtin_amdgcn_exp2f(2.8853900817779268f * a);
        const float th = 1.0f - 2.0f * __builtin_amdgcn_rcpf(1.0f + ex);
        acc = fmaf(w2[j], th, acc);
    }
    tabg[e] = acc;
}

__device__ __forceinline__ float soen_g3_exact(float p, float svv, float ibl,
        const float* __restrict__ w1, const float* __restrict__ b1,
        const float* __restrict__ w2, const float* __restrict__ b2)
{
    float acc = b2[0];
    for (int j = 0; j < HID; j++) {
        const float a = fmaf(p, w1[j], fmaf(svv, w1[HID + j], fmaf(ibl, w1[2 * HID + j], b1[j])));
        const float ex = __builtin_amdgcn_exp2f(2.8853900817779268f * a);
        const float th = 1.0f - 2.0f * __builtin_amdgcn_rcpf(1.0f + ex);
        acc = fmaf(w2[j], th, acc);
    }
    return acc;
}

// branchless per-element: computes g0..g2 and bilinear-table g3, selects by idx
__device__ __forceinline__ float soen_elem(float phv, float svv, int idx,
                                           const float* __restrict__ tab)
{
    const float p  = phv - rintf(phv);                     // half-to-even, matches jnp.round
    const float p2 = p * p;
    const float g0 = fmaxf(fabsf(p) - svv, 0.f);
    // tanh(p), |p|<=0.5, odd series err<5e-4
    const float tp = p * fmaf(p2, fmaf(p2, 0.13333333f, -0.33333333f), 1.f);
    const float g1 = fmaf(-tp, svv, tp);
    const float g2 = __builtin_amdgcn_exp2f(-14.426950408889634f * p2) - svv;
    // bilinear lookup (unconditional -- mixed-idx waves pay both paths anyway)
    const float u  = fmaf(p, PSCALE, 0.5f * PSCALE);       // [0,63]
    const float vv = svv * SSCALE;                         // [0,63)
    int iu = (int)u;  iu = iu > TP - 2 ? TP - 2 : iu;      // u,vv >= 0 -> trunc ok
    int iv = (int)vv; iv = iv > TS - 2 ? TS - 2 : iv;
    const float du = u - (float)iu;
    const float dv = vv - (float)iv;
    const float* bp = tab + iu * TST + iv;
    const float t00 = bp[0],   t01 = bp[1];                // ds_read2_b32 pair
    const float t10 = bp[TST], t11 = bp[TST + 1];          // ds_read2_b32 pair
    const float a0 = fmaf(dv, t01 - t00, t00);
    const float a1 = fmaf(dv, t11 - t10, t10);
    const float g3 = fmaf(du, a1 - a0, a0);
    return (idx == 0) ? g0 : (idx == 1) ? g1 : (idx == 2) ? g2 : g3;
}

__global__ __launch_bounds__(THREADS, 4) void soen_main(   // cap 128 VGPR: keep batch in regs
    const float* __restrict__ phi, const float* __restrict__ s,
    const float* __restrict__ i_b, const float* __restrict__ w1,
    const float* __restrict__ b1, const float* __restrict__ w2,
    const float* __restrict__ b2, const int* __restrict__ func_idx,
    const float* __restrict__ tabg, float* __restrict__ out)
{
    __shared__ float tab[TP * TST];                        // 17.4 KB

    const int t = threadIdx.x;
    // stage table (4096 floats = 1024 float4 = 4 iters), global linear -> padded LDS
    for (int i = t; i < TP * TS / 4; i += THREADS) {
        const float4 v = ((const float4*)tabg)[i];
        const int e = i << 2;
        const int r = e >> 6;                              // e / TS
        const int c = e & 63;                              // multiple of 4
        *(float4*)&tab[r * TST + c] = v;                   // aligned: TST%4==0
    }

    const int col = blockIdx.x * CPB + (t << 2);
    const int rowbase = blockIdx.y * RPB;
    const int4   fidx = *(const int4*)(func_idx + col);
    const float4 ib4  = *(const float4*)(i_b + col);
    const float  ib0  = i_b[0];
    const bool anyExact = __any((fidx.x == 3 && ib4.x != ib0) || (fidx.y == 3 && ib4.y != ib0) ||
                                (fidx.z == 3 && ib4.z != ib0) || (fidx.w == 3 && ib4.w != ib0));

    const size_t base = (size_t)rowbase * NCOLS + col;
    const float4* pp = (const float4*)(phi + base);
    const float4* sp = (const float4*)(s + base);
    float4*       po = (float4*)(out + base);
    const int STR = NCOLS / 4;

    __syncthreads();

    auto c4 = [&](float4 P, float4 S) -> float4 {
        float4 o;
        o.x = soen_elem(P.x, S.x, fidx.x, tab);
        o.y = soen_elem(P.y, S.y, fidx.y, tab);
        o.z = soen_elem(P.z, S.z, fidx.z, tab);
        o.w = soen_elem(P.w, S.w, fidx.w, tab);
        if (anyExact) {                                    // wave-uniformly false on this data
            if (fidx.x == 3 && ib4.x != ib0) o.x = soen_g3_exact(P.x - rintf(P.x), S.x, ib4.x, w1, b1, w2, b2);
            if (fidx.y == 3 && ib4.y != ib0) o.y = soen_g3_exact(P.y - rintf(P.y), S.y, ib4.y, w1, b1, w2, b2);
            if (fidx.z == 3 && ib4.z != ib0) o.z = soen_g3_exact(P.z - rintf(P.z), S.z, ib4.z, w1, b1, w2, b2);
            if (fidx.w == 3 && ib4.w != ib0) o.w = soen_g3_exact(P.w - rintf(P.w), S.w, ib4.w, w1, b1, w2, b2);
        }
        return o;
    };

    // 2-row lookahead software pipeline, named vars only (no dynamic indexing)
    float4 pA = pp[0],   sA = sp[0];
    float4 pB = pp[STR], sB = sp[STR];
    #pragma unroll
    for (int r = 0; r < RPB; r += 2) {
        float4 pC, sC, pD, sD;
        if (r + 2 < RPB) {                                 // compile-time per unrolled iter
            pC = pp[(size_t)(r + 2) * STR]; sC = sp[(size_t)(r + 2) * STR];
            pD = pp[(size_t)(r + 3) * STR]; sD = sp[(size_t)(r + 3) * STR];
        }
        po[(size_t)r * STR]       = c4(pA, sA);
        po[(size_t)(r + 1) * STR] = c4(pB, sB);
        pA = pC; sA = sC; pB = pD; sB = sD;                // SSA-renamed away by full unroll
    }
}

extern "C" void kernel_launch(void* const* d_in, const int* in_sizes, int n_in,
                              void* d_out, int out_size, void* d_ws, size_t ws_size,
                              hipStream_t stream)
{
    const float* phi      = (const float*)d_in[0];
    const float* s        = (const float*)d_in[1];
    const float* i_b      = (const float*)d_in[2];
    const float* w1       = (const float*)d_in[3];
    const float* b1       = (const float*)d_in[4];
    const float* w2       = (const float*)d_in[5];
    const float* b2       = (const float*)d_in[6];
    const int*   func_idx = (const int*)d_in[7];
    float* outp = (float*)d_out;
    float* tabg = (float*)d_ws;                            // needs TP*TS*4 = 16 KB of workspace

    soen_build<<<dim3(TP * TS / THREADS), dim3(THREADS), 0, stream>>>(i_b, w1, b1, w2, b2, tabg);

    dim3 grid(NCOLS / CPB, NROWS / RPB);                   // 64 x 16 = 1024 blocks
    soen_main<<<grid, dim3(THREADS), 0, stream>>>(phi, s, i_b, w1, b1, w2, b2, func_idx,
                                                  tabg, outp);
}